// Round 5
// baseline (292.500 us; speedup 1.0000x reference)
//
#include <hip/hip_runtime.h>
#include <stdint.h>

// DCT2D: y = Dh @ x @ Dw^T per (b,c); B=32,H=W=512,C=3, fp32 in/out.
// bf16 MFMA (16x16x32), two GEMM passes via bf16 intermediate Y[b,k,c,w].
// R5: mt/lt PAIRING. R1-R4 established: scheduling null (R1,R3), BK=64 hurts
// via occupancy (R4); kernel is latency-bound, throughput = resident blocks /
// total block-iterations. Pass1 packed the same x-tile 4x (once per mt);
// pass2 staged the same Y-tile 4x (once per lt). Now each block owns TWO
// m/l tiles: half the blocks, pack/stage shared, 24 MFMA/wave/iter,
// acc 96 VGPR. Simple R0 schedule (2 syncthreads/iter), BK=32.

typedef __bf16 bf16_t;
typedef bf16_t bf16x8 __attribute__((ext_vector_type(8)));
typedef float  f32x4  __attribute__((ext_vector_type(4)));

__device__ __forceinline__ uint32_t f2bf(float f) {
    union { float f; uint32_t u; } v; v.f = f;
    uint32_t r = v.u + 0x7fffu + ((v.u >> 16) & 1u);   // RNE
    return r >> 16;
}

__device__ __forceinline__ f32x4 mfma16(bf16x8 a, bf16x8 b, f32x4 c) {
    return __builtin_amdgcn_mfma_f32_16x16x32_bf16(a, b, c, 0, 0, 0);
}

__device__ __forceinline__ void load_lds16(const void* g, void* l) {
    __builtin_amdgcn_global_load_lds(
        (const __attribute__((address_space(1))) uint32_t*)g,
        (__attribute__((address_space(3))) uint32_t*)l, 16, 0, 0);
}

// ---------------- D matrix generation (bf16, row-major D[k][h]) -------------
__global__ __launch_bounds__(256) void gen_dct(uint16_t* __restrict__ Dbf) {
    int idx = blockIdx.x * 256 + threadIdx.x;      // 512*512 elems
    int k = idx >> 9, h = idx & 511;
    int phase = ((2 * h + 1) * k) & 2047;          // exact mod-2048 reduction
    float ang = (float)phase * 3.0679615757712823e-3f;   // pi/1024
    float s = (k == 0) ? 0.04419417382415922f : 0.0625f; // sqrt(1/512), sqrt(2/512)
    Dbf[idx] = (uint16_t)f2bf(__cosf(ang) * s);
}

// ---------------- Pass 1: Y[b,k,c,w] = sum_h D[k,h] * x[b,h,w,c] ------------
// GEMM per b: C[m=k(2x128-tile), n=remapped (c,w) col (96-tile)], K=h, BK=32.
// Each block owns TWO k-tiles (256 rows of D): x-tile gathered+packed ONCE.
// A = D rows [mp*256, mp*256+256) via global_load_lds, chunk-swizzled
//     (slot i holds global chunk i ^ ((row>>1)&3); read applies same XOR).
// B = x tile fp32->bf16 transposed to [col][h], 3-term XOR swizzle.
__global__ __launch_bounds__(256, 3) void pass1(const float* __restrict__ x,
                                                const uint16_t* __restrict__ Dbf,
                                                uint16_t* __restrict__ Y) {
    __shared__ __align__(16) uint16_t Alds[256 * 32];   // 16 KB (two 128-tiles)
    __shared__ __align__(16) uint16_t Blds[96 * 32];    // 6 KB
    const int t = threadIdx.x;
    const int lane = t & 63, wv = t >> 6;
    const int nt = blockIdx.x;   // j-tile 0..15 (96 cols = 32 w * 3 c)
    const int mp = blockIdx.y;   // k-tile PAIR 0..1 (rows mp*256 .. +255)
    const int b  = blockIdx.z;
    const float* xb = x + (size_t)b * (512 * 1536);

    // A staging: 1024 chunks, 4/thread. slot q -> row m=q>>2, holds global
    // chunk (q&3) ^ ((m>>1)&3).
    const int q0 = t, q1 = t + 256, q2 = t + 512, q3 = t + 768;
    const int m0 = q0 >> 2, i0 = (q0 & 3) ^ ((m0 >> 1) & 3);
    const int m1 = q1 >> 2, i1 = (q1 & 3) ^ ((m1 >> 1) & 3);
    const int m2 = q2 >> 2, i2 = (q2 & 3) ^ ((m2 >> 1) & 3);
    const int m3 = q3 >> 2, i3 = (q3 & 3) ^ ((m3 >> 1) & 3);
    const uint16_t* As0 = Dbf + (size_t)(mp * 256 + m0) * 512 + i0 * 8;
    const uint16_t* As1 = Dbf + (size_t)(mp * 256 + m1) * 512 + i1 * 8;
    const uint16_t* As2 = Dbf + (size_t)(mp * 256 + m2) * 512 + i2 * 8;
    const uint16_t* As3 = Dbf + (size_t)(mp * 256 + m3) * 512 + i3 * 8;

    // B-staging mapping (threads 0..191): jl -> (w,c); col remap so that
    // MFMA col-tiles 2c/2c+1 hold even/odd w (paired bf16 stores).
    const int jl = t % 96;
    const int hh = t / 96;                       // 0/1 -> h-halves of 16
    const int wl = jl / 3, cc = jl - 3 * wl;
    const int ncol = cc * 32 + ((wl >> 1) + ((wl & 1) << 4));
    const int xv = ((ncol >> 1) ^ (ncol >> 3) ^ (ncol >> 5)) & 3;  // chunk XOR
    const int jg = nt * 96 + jl;
    const float* xsrc = xb + (size_t)(hh * 16) * 1536 + jg;

    f32x4 acc[2][2][6] = {};     // [mtk][i][tt]

    for (int kt = 0; kt < 16; ++kt) {
        __syncthreads();
        // A: two D 128-tiles (256 rows x 64 B)
        load_lds16(As0 + kt * 32, Alds + q0 * 8);
        load_lds16(As1 + kt * 32, Alds + q1 * 8);
        load_lds16(As2 + kt * 32, Alds + q2 * 8);
        load_lds16(As3 + kt * 32, Alds + q3 * 8);
        // B: x tile 32h x 96j fp32 -> bf16, transposed to [col][h]
        if (t < 192) {
            const float* src = xsrc + (size_t)kt * 32 * 1536;
            float v[16];
#pragma unroll
            for (int r = 0; r < 16; ++r) v[r] = src[(size_t)r * 1536];
            uint32_t p[8];
#pragma unroll
            for (int i = 0; i < 8; ++i)
                p[i] = f2bf(v[2 * i]) | (f2bf(v[2 * i + 1]) << 16);
            *(uint4*)&Blds[ncol * 32 + (((hh * 2 + 0) ^ xv) << 3)] =
                make_uint4(p[0], p[1], p[2], p[3]);
            *(uint4*)&Blds[ncol * 32 + (((hh * 2 + 1) ^ xv) << 3)] =
                make_uint4(p[4], p[5], p[6], p[7]);
        }
        __syncthreads();

        bf16x8 aq[2][2];
#pragma unroll
        for (int mtk = 0; mtk < 2; ++mtk)
#pragma unroll
            for (int i = 0; i < 2; ++i) {
                int row = mtk * 128 + (wv * 2 + i) * 16 + (lane & 15);
                aq[mtk][i] = *(const bf16x8*)&Alds[row * 32 +
                                (((lane >> 4) ^ ((row >> 1) & 3)) << 3)];
            }
#pragma unroll
        for (int tt = 0; tt < 6; ++tt) {
            int col = tt * 16 + (lane & 15);
            int xr = ((col >> 1) ^ (col >> 3) ^ (col >> 5)) & 3;
            bf16x8 bq = *(const bf16x8*)&Blds[col * 32 + (((lane >> 4) ^ xr) << 3)];
#pragma unroll
            for (int mtk = 0; mtk < 2; ++mtk) {
                acc[mtk][0][tt] = mfma16(aq[mtk][0], bq, acc[mtk][0][tt]);
                acc[mtk][1][tt] = mfma16(aq[mtk][1], bq, acc[mtk][1][tt]);
            }
        }
    }

    // Epilogue: direct coalesced dword stores (bf16 pair at adjacent w).
    const int wg = nt * 32 + 2 * (lane & 15);
#pragma unroll
    for (int mtk = 0; mtk < 2; ++mtk)
#pragma unroll
        for (int i = 0; i < 2; ++i) {
            int kg = mp * 256 + mtk * 128 + (wv * 2 + i) * 16 + ((lane >> 4) << 2);
#pragma unroll
            for (int c = 0; c < 3; ++c)
#pragma unroll
                for (int r = 0; r < 4; ++r) {
                    uint32_t pk = f2bf(acc[mtk][i][2 * c][r]) |
                                  (f2bf(acc[mtk][i][2 * c + 1][r]) << 16);
                    *(uint32_t*)&Y[(size_t)b * 786432 + (size_t)(kg + r) * 1536 +
                                   c * 512 + wg] = pk;
                }
        }
}

// ---------------- Pass 2: out[b,k,l,c] = sum_w D[l,w] * Y[b,k,c,w] ----------
// GEMM per b: C[m=kc(96-tile), n=l(2x128-tile)], K=w, BK=32.
// Each block owns TWO l-tiles (256 D rows): Y-tile staged ONCE per iter.
__global__ __launch_bounds__(256, 3) void pass2(const uint16_t* __restrict__ Y,
                                                const uint16_t* __restrict__ Dbf,
                                                float* __restrict__ out) {
    __shared__ __align__(16) char smem[24960];     // max(staging 22528, El 24960)
    uint16_t* Alds = (uint16_t*)smem;              // 96*32 bf16 = 6144 B
    uint16_t* Blds = (uint16_t*)(smem + 6144);     // 256*32 bf16 = 16384 B
    float*    El   = (float*)smem;                 // 96 x 65 fp32 epilogue
    const int t = threadIdx.x;
    const int lane = t & 63, wv = t >> 6;
    const int lp = blockIdx.x;   // l-tile PAIR 0..1 (l rows lp*256 .. +255)
    const int mt = blockIdx.y;   // kc-tile 0..15
    const int b  = blockIdx.z;
    const size_t yb = (size_t)b * 786432;

    // A: 384 slots (1.5/thread); B: 1024 slots (4/thread). Chunk swizzle as pass1.
    const int q0 = t, q1 = t + 256, q2 = t + 512, q3 = t + 768;
    const int m0 = q0 >> 2, i0 = (q0 & 3) ^ ((m0 >> 1) & 3);
    const int m1 = q1 >> 2, i1 = (q1 & 3) ^ ((m1 >> 1) & 3);
    const int m2 = q2 >> 2, i2 = (q2 & 3) ^ ((m2 >> 1) & 3);
    const int m3 = q3 >> 2, i3 = (q3 & 3) ^ ((m3 >> 1) & 3);

    const uint16_t* Ys0 = Y + yb + (size_t)(mt * 96 + m0) * 512 + i0 * 8;
    const uint16_t* Ys1 = Y + yb + (size_t)(mt * 96 + m1) * 512 + i1 * 8;  // t<128
    const uint16_t* Ds0 = Dbf + (size_t)(lp * 256 + m0) * 512 + i0 * 8;
    const uint16_t* Ds1 = Dbf + (size_t)(lp * 256 + m1) * 512 + i1 * 8;
    const uint16_t* Ds2 = Dbf + (size_t)(lp * 256 + m2) * 512 + i2 * 8;
    const uint16_t* Ds3 = Dbf + (size_t)(lp * 256 + m3) * 512 + i3 * 8;

    f32x4 acc[6][2][2] = {};     // [tt][p][lt2]

    for (int kt = 0; kt < 16; ++kt) {
        __syncthreads();
        load_lds16(Ys0 + kt * 32, Alds + q0 * 8);
        if (t < 128) load_lds16(Ys1 + kt * 32, Alds + q1 * 8);
        load_lds16(Ds0 + kt * 32, Blds + q0 * 8);
        load_lds16(Ds1 + kt * 32, Blds + q1 * 8);
        load_lds16(Ds2 + kt * 32, Blds + q2 * 8);
        load_lds16(Ds3 + kt * 32, Blds + q3 * 8);
        __syncthreads();

        bf16x8 bq[2][2];
#pragma unroll
        for (int lt2 = 0; lt2 < 2; ++lt2)
#pragma unroll
            for (int p = 0; p < 2; ++p) {
                int row = lt2 * 128 + (wv * 2 + p) * 16 + (lane & 15);
                bq[lt2][p] = *(const bf16x8*)&Blds[row * 32 +
                                (((lane >> 4) ^ ((row >> 1) & 3)) << 3)];
            }
#pragma unroll
        for (int tt = 0; tt < 6; ++tt) {
            int row = tt * 16 + (lane & 15);
            bf16x8 aq = *(const bf16x8*)&Alds[row * 32 +
                            (((lane >> 4) ^ ((row >> 1) & 3)) << 3)];
#pragma unroll
            for (int lt2 = 0; lt2 < 2; ++lt2) {
                acc[tt][0][lt2] = mfma16(aq, bq[lt2][0], acc[tt][0][lt2]);
                acc[tt][1][lt2] = mfma16(aq, bq[lt2][1], acc[tt][1][lt2]);
            }
        }
    }

    // Epilogue: per lt2 and l-half, transpose [kc][l] -> out rows [k][(l,c)]
    // via padded LDS (96 x 65 fp32 = 24960 B, aliases staging).
    const int kloc = t >> 3, sub = t & 7;   // 32 k-rows, 8 threads per row
#pragma unroll
    for (int lt2 = 0; lt2 < 2; ++lt2) {
        const int lte = lp * 2 + lt2;       // effective 128-l tile 0..3
#pragma unroll
        for (int hf = 0; hf < 2; ++hf) {
            __syncthreads();
            if ((wv >> 1) == hf) {          // waves owning l in [hf*64, hf*64+64)
#pragma unroll
                for (int tt = 0; tt < 6; ++tt)
#pragma unroll
                    for (int p = 0; p < 2; ++p) {
                        int m = tt * 16 + ((lane >> 4) << 2);
                        int lc = ((wv & 1) * 2 + p) * 16 + (lane & 15);
#pragma unroll
                        for (int r = 0; r < 4; ++r)
                            El[(m + r) * 65 + lc] = acc[tt][p][lt2][r];
                    }
            }
            __syncthreads();
            size_t ob = (size_t)b * 786432 + (size_t)(mt * 32 + kloc) * 1536 +
                        lte * 384 + hf * 192 + sub * 24;
#pragma unroll
            for (int q = 0; q < 6; ++q) {
                int o0 = hf * 192 + sub * 24 + q * 4;
                float4 v;
                v.x = El[(kloc * 3 + ((o0 + 0) % 3)) * 65 + ((o0 + 0) / 3 - hf * 64)];
                v.y = El[(kloc * 3 + ((o0 + 1) % 3)) * 65 + ((o0 + 1) / 3 - hf * 64)];
                v.z = El[(kloc * 3 + ((o0 + 2) % 3)) * 65 + ((o0 + 2) / 3 - hf * 64)];
                v.w = El[(kloc * 3 + ((o0 + 3) % 3)) * 65 + ((o0 + 3) / 3 - hf * 64)];
                *(float4*)&out[ob + q * 4] = v;
            }
        }
    }
}

// ---------------------------------------------------------------------------
extern "C" void kernel_launch(void* const* d_in, const int* in_sizes, int n_in,
                              void* d_out, int out_size, void* d_ws, size_t ws_size,
                              hipStream_t stream) {
    (void)in_sizes; (void)n_in; (void)out_size; (void)ws_size;
    const float* x = (const float*)d_in[0];
    float* out = (float*)d_out;
    uint16_t* Dbf = (uint16_t*)d_ws;                 // 512*512 bf16 = 512 KB
    uint16_t* Y   = (uint16_t*)d_ws + 512 * 512;     // 32*512*512*3 bf16 = 48 MB

    gen_dct<<<1024, 256, 0, stream>>>(Dbf);
    dim3 g1(16, 2, 32);
    pass1<<<g1, 256, 0, stream>>>(x, Dbf, Y);
    dim3 g2(2, 16, 32);
    pass2<<<g2, 256, 0, stream>>>(Y, Dbf, out);
}

// Round 6
// 278.643 us; speedup vs baseline: 1.0497x; 1.0497x over previous
//
#include <hip/hip_runtime.h>
#include <stdint.h>

// DCT2D: y = Dh @ x @ Dw^T per (b,c); B=32,H=W=512,C=3, fp32 in/out.
// R6 RESTRUCTURE. R0-R5 showed both passes run at the m97-structure ceiling
// (~300 TF at this size); schedule tweaks null, small tiles are the wall.
// New: convert-once kernel (x fp32 -> Xt bf16 [b][jr][h]) + two big-tile
// 512-thread GEMMs (BK=64, 8 K-iters, both operands via global_load_lds,
// ^(row&7) source-chunk swizzle). G1: 128k x 256j, grid 768 (=3 exact CU
// generations). G2: 96kc x 256l, grid 1024 (2 blocks/CU). Simple 2-barrier
// loop (proven schedule-insensitive).

typedef __bf16 bf16_t;
typedef bf16_t bf16x8 __attribute__((ext_vector_type(8)));
typedef float  f32x4  __attribute__((ext_vector_type(4)));

__device__ __forceinline__ uint32_t f2bf(float f) {
    union { float f; uint32_t u; } v; v.f = f;
    uint32_t r = v.u + 0x7fffu + ((v.u >> 16) & 1u);   // RNE
    return r >> 16;
}

__device__ __forceinline__ f32x4 mfma16(bf16x8 a, bf16x8 b, f32x4 c) {
    return __builtin_amdgcn_mfma_f32_16x16x32_bf16(a, b, c, 0, 0, 0);
}

__device__ __forceinline__ void load_lds16(const void* g, void* l) {
    __builtin_amdgcn_global_load_lds(
        (const __attribute__((address_space(1))) uint32_t*)g,
        (__attribute__((address_space(3))) uint32_t*)l, 16, 0, 0);
}

// ---------------- D matrix generation (bf16, row-major D[k][h]) -------------
__global__ __launch_bounds__(256) void gen_dct(uint16_t* __restrict__ Dbf) {
    int idx = blockIdx.x * 256 + threadIdx.x;      // 512*512 elems
    int k = idx >> 9, h = idx & 511;
    int phase = ((2 * h + 1) * k) & 2047;          // exact mod-2048 reduction
    float ang = (float)phase * 3.0679615757712823e-3f;   // pi/1024
    float s = (k == 0) ? 0.04419417382415922f : 0.0625f; // sqrt(1/512), sqrt(2/512)
    Dbf[idx] = (uint16_t)f2bf(__cosf(ang) * s);
}

// ---------------- xpose: x[b][h][w][c] fp32 -> Xt[b][jr][h] bf16 ------------
// jr = c*512 + wr, wr = (w>>8)*256 + ((w&255)>>1) + ((w&1)<<7)  (within-256
// even/odd pairing so G1's epilogue can store adjacent-w bf16 pairs as dwords).
// No LDS: each thread packs 16 h-contiguous values of one column -> 2 x 16B
// stores. Grid (12 jt, 16 hb, 32 b), 256 thr.
__global__ __launch_bounds__(256) void xpose(const float* __restrict__ x,
                                             uint16_t* __restrict__ Xt) {
    const int jt = blockIdx.x, hb = blockIdx.y, b = blockIdx.z;
    const int t = threadIdx.x;
    const int jl = t & 127, hh = t >> 7;           // 128 cols x 2 h-halves
    const int jg = jt * 128 + jl;                  // raw col = w*3 + c
    const int w = jg / 3, c = jg - 3 * w;
    const int wr = ((w >> 8) << 8) + ((w & 255) >> 1) + ((w & 1) << 7);
    const int jr = c * 512 + wr;
    const float* src = x + (size_t)b * 786432 +
                       (size_t)(hb * 32 + hh * 16) * 1536 + jg;
    float v[16];
#pragma unroll
    for (int r = 0; r < 16; ++r) v[r] = src[(size_t)r * 1536];
    uint32_t p[8];
#pragma unroll
    for (int i = 0; i < 8; ++i)
        p[i] = f2bf(v[2 * i]) | (f2bf(v[2 * i + 1]) << 16);
    size_t dst = ((size_t)b * 1536 + jr) * 512 + hb * 32 + hh * 16;
    *(uint4*)&Xt[dst]     = make_uint4(p[0], p[1], p[2], p[3]);
    *(uint4*)&Xt[dst + 8] = make_uint4(p[4], p[5], p[6], p[7]);
}

// ---------------- G1: Y[b,k,c,w] = sum_h D[k,h] * x[b,h,(c,w)] --------------
// Per b: C[m=k(128-tile)][n=jr(256-tile)], K=h, BK=64, 8 iters.
// A = D rows (gload_lds, chunk^(row&7) src swizzle); B = Xt rows (same).
// 8 waves 2m x 4n; wave-tile 64k x 64j with n-frags at col-tiles wn+4f
// (so even/odd-w pair tiles u,u+8 live in the same wave).
__global__ __launch_bounds__(512, 2) void gemm1(const uint16_t* __restrict__ Xt,
                                                const uint16_t* __restrict__ Dbf,
                                                uint16_t* __restrict__ Y) {
    __shared__ __align__(16) uint16_t Al[128 * 64];   // 16 KB
    __shared__ __align__(16) uint16_t Bl[256 * 64];   // 32 KB
    const int t = threadIdx.x;
    const int lane = t & 63, wv = t >> 6;
    const int wm = wv >> 2, wn = wv & 3;
    const int nt = blockIdx.x;   // j-tile 0..5 (c = nt>>1, w-half = nt&1)
    const int mt = blockIdx.y;   // k-tile 0..3
    const int b  = blockIdx.z;

    // A staging: 1024 slots (2/thread). slot q -> row m=q>>3, holds global
    // chunk (q&7)^(m&7) of the row (involution; read applies same XOR).
    const int qa0 = t, qa1 = t + 512;
    const int ma0 = qa0 >> 3, ga0 = (qa0 & 7) ^ (ma0 & 7);
    const int ma1 = qa1 >> 3, ga1 = (qa1 & 7) ^ (ma1 & 7);
    const uint16_t* As0 = Dbf + (size_t)(mt * 128 + ma0) * 512 + ga0 * 8;
    const uint16_t* As1 = Dbf + (size_t)(mt * 128 + ma1) * 512 + ga1 * 8;
    // B staging: 2048 slots (4/thread)
    const uint16_t* Bs[4];
    int qb[4];
#pragma unroll
    for (int i = 0; i < 4; ++i) {
        qb[i] = t + 512 * i;
        int mb = qb[i] >> 3, gb = (qb[i] & 7) ^ (mb & 7);
        Bs[i] = Xt + ((size_t)b * 1536 + nt * 256 + mb) * 512 + gb * 8;
    }

    f32x4 acc[4][4] = {};   // [mf][f]

    for (int kt = 0; kt < 8; ++kt) {
        __syncthreads();
        load_lds16(As0 + kt * 64, Al + qa0 * 8);
        load_lds16(As1 + kt * 64, Al + qa1 * 8);
#pragma unroll
        for (int i = 0; i < 4; ++i)
            load_lds16(Bs[i] + kt * 64, Bl + qb[i] * 8);
        __syncthreads();

#pragma unroll
        for (int ks = 0; ks < 2; ++ks) {
            bf16x8 aq[4], bq[4];
#pragma unroll
            for (int mf = 0; mf < 4; ++mf) {
                int row = wm * 64 + mf * 16 + (lane & 15);
                int sl = (ks * 4 + (lane >> 4)) ^ (row & 7);
                aq[mf] = *(const bf16x8*)&Al[row * 64 + sl * 8];
            }
#pragma unroll
            for (int f = 0; f < 4; ++f) {
                int col = (wn + 4 * f) * 16 + (lane & 15);
                int sl = (ks * 4 + (lane >> 4)) ^ (col & 7);
                bq[f] = *(const bf16x8*)&Bl[col * 64 + sl * 8];
            }
#pragma unroll
            for (int mf = 0; mf < 4; ++mf)
#pragma unroll
                for (int f = 0; f < 4; ++f)
                    acc[mf][f] = mfma16(aq[mf], bq[f], acc[mf][f]);
        }
    }

    // Epilogue: pair col-tiles (u, u+8) = (f, f+2) -> dword stores of two
    // bf16 at adjacent w. Y[b][k][c][w].
    const int cch = nt >> 1, whalf = nt & 1;
#pragma unroll
    for (int mf = 0; mf < 4; ++mf)
#pragma unroll
        for (int fp = 0; fp < 2; ++fp) {
            int kbase = mt * 128 + wm * 64 + mf * 16 + ((lane >> 4) << 2);
            int u = wn + 4 * fp;
            int w = whalf * 256 + 2 * (u * 16 + (lane & 15));
#pragma unroll
            for (int r = 0; r < 4; ++r) {
                uint32_t pk = f2bf(acc[mf][fp][r]) |
                              (f2bf(acc[mf][fp + 2][r]) << 16);
                *(uint32_t*)&Y[(size_t)b * 786432 + (size_t)(kbase + r) * 1536 +
                               cch * 512 + w] = pk;
            }
        }
}

// ---------------- G2: out[b,k,l,c] = sum_w D[l,w] * Y[b,k,c,w] --------------
// Per b: C[m=kc(96-tile)][n=l(256-tile)], K=w, BK=64, 8 iters.
// A = Y rows kc (w-contig), B = D rows l. 8 waves 2m x 4n; wave 48kc x 64l.
// Epilogue: 2 rounds (wm) of 48x257 fp32 LDS transpose -> coalesced float4.
__global__ __launch_bounds__(512, 4) void gemm2(const uint16_t* __restrict__ Y,
                                                const uint16_t* __restrict__ Dbf,
                                                float* __restrict__ out) {
    __shared__ __align__(16) char smem[49408];   // staging 45056 | El 49344
    uint16_t* Al = (uint16_t*)smem;              // 96*64 bf16 = 12288 B
    uint16_t* Bl = (uint16_t*)(smem + 12288);    // 256*64 bf16 = 32768 B
    float*    El = (float*)smem;                 // 48 x 257 fp32 epilogue
    const int t = threadIdx.x;
    const int lane = t & 63, wv = t >> 6;
    const int wm = wv >> 2, wn = wv & 3;
    const int mt = blockIdx.x;   // kc-tile 0..15
    const int lt = blockIdx.y;   // l-tile 0..1
    const int b  = blockIdx.z;
    const size_t yb = (size_t)b * 786432;

    // A: 768 slots (t, +512 for t<256); B: 2048 slots (4/thread)
    const int qa0 = t, qa1 = t + 512;
    const int ma0 = qa0 >> 3, ga0 = (qa0 & 7) ^ (ma0 & 7);
    const int ma1 = qa1 >> 3, ga1 = (qa1 & 7) ^ (ma1 & 7);
    const uint16_t* As0 = Y + yb + (size_t)(mt * 96 + ma0) * 512 + ga0 * 8;
    const uint16_t* As1 = Y + yb + (size_t)(mt * 96 + ma1) * 512 + ga1 * 8;
    const uint16_t* Bs[4];
    int qb[4];
#pragma unroll
    for (int i = 0; i < 4; ++i) {
        qb[i] = t + 512 * i;
        int mb = qb[i] >> 3, gb = (qb[i] & 7) ^ (mb & 7);
        Bs[i] = Dbf + (size_t)(lt * 256 + mb) * 512 + gb * 8;
    }

    f32x4 acc[3][4] = {};   // [mf][f]

    for (int kt = 0; kt < 8; ++kt) {
        __syncthreads();
        load_lds16(As0 + kt * 64, Al + qa0 * 8);
        if (t < 256) load_lds16(As1 + kt * 64, Al + qa1 * 8);
#pragma unroll
        for (int i = 0; i < 4; ++i)
            load_lds16(Bs[i] + kt * 64, Bl + qb[i] * 8);
        __syncthreads();

#pragma unroll
        for (int ks = 0; ks < 2; ++ks) {
            bf16x8 aq[3], bq[4];
#pragma unroll
            for (int mf = 0; mf < 3; ++mf) {
                int row = wm * 48 + mf * 16 + (lane & 15);
                int sl = (ks * 4 + (lane >> 4)) ^ (row & 7);
                aq[mf] = *(const bf16x8*)&Al[row * 64 + sl * 8];
            }
#pragma unroll
            for (int f = 0; f < 4; ++f) {
                int col = wn * 64 + f * 16 + (lane & 15);
                int sl = (ks * 4 + (lane >> 4)) ^ (col & 7);
                bq[f] = *(const bf16x8*)&Bl[col * 64 + sl * 8];
            }
#pragma unroll
            for (int mf = 0; mf < 3; ++mf)
#pragma unroll
                for (int f = 0; f < 4; ++f)
                    acc[mf][f] = mfma16(aq[mf], bq[f], acc[mf][f]);
        }
    }

    // Epilogue: rounds over wm-half (48 kc = 16 k x 3 c each, k-aligned since
    // 48%3==0). El[kc_local][l_local] pitch 257; out stores are contiguous
    // float4: out flat per k-row = k*1536 + lt*768 + z, z in [0,768).
    const int kloc = t >> 5, zrow = t & 31;   // 16 k-rows, 32 thr/row
#pragma unroll
    for (int rnd = 0; rnd < 2; ++rnd) {
        __syncthreads();
        if (wm == rnd) {
#pragma unroll
            for (int mf = 0; mf < 3; ++mf)
#pragma unroll
                for (int f = 0; f < 4; ++f) {
                    int row = mf * 16 + ((lane >> 4) << 2);
                    int col = wn * 64 + f * 16 + (lane & 15);
#pragma unroll
                    for (int r = 0; r < 4; ++r)
                        El[(row + r) * 257 + col] = acc[mf][f][r];
                }
        }
        __syncthreads();
        int kbase = mt * 32 + rnd * 16;
        size_t ob = (size_t)b * 786432 + (size_t)(kbase + kloc) * 1536 + lt * 768;
#pragma unroll
        for (int q4 = 0; q4 < 6; ++q4) {
            int z0 = zrow * 24 + q4 * 4;
            float4 v;
            v.x = El[(kloc * 3 + ((z0 + 0) % 3)) * 257 + (z0 + 0) / 3];
            v.y = El[(kloc * 3 + ((z0 + 1) % 3)) * 257 + (z0 + 1) / 3];
            v.z = El[(kloc * 3 + ((z0 + 2) % 3)) * 257 + (z0 + 2) / 3];
            v.w = El[(kloc * 3 + ((z0 + 3) % 3)) * 257 + (z0 + 3) / 3];
            *(float4*)&out[ob + z0] = v;
        }
    }
}

// ---------------------------------------------------------------------------
extern "C" void kernel_launch(void* const* d_in, const int* in_sizes, int n_in,
                              void* d_out, int out_size, void* d_ws, size_t ws_size,
                              hipStream_t stream) {
    (void)in_sizes; (void)n_in; (void)out_size;
    const float* x = (const float*)d_in[0];
    float* out = (float*)d_out;
    uint16_t* Dbf = (uint16_t*)d_ws;                 // 512*512 bf16 = 512 KB
    uint16_t* Yw  = (uint16_t*)d_ws + 512 * 512;     // 32*512*512*3 bf16 = 48 MB
    // Xt (48 MB): in d_ws if it fits, else scratch in d_out (G2 overwrites
    // out only after G1 has finished reading Xt; kernels are stream-ordered).
    size_t need = (size_t)512 * 512 * 2 + (size_t)2 * 32 * 1536 * 512 * 2;
    uint16_t* Xt = (ws_size >= need)
                     ? (uint16_t*)d_ws + 512 * 512 + (size_t)32 * 1536 * 512
                     : (uint16_t*)d_out;

    gen_dct<<<1024, 256, 0, stream>>>(Dbf);
    dim3 gt(12, 16, 32);
    xpose<<<gt, 256, 0, stream>>>(x, Xt);
    dim3 g1(6, 4, 32);
    gemm1<<<g1, 512, 0, stream>>>(Xt, Dbf, Yw);
    dim3 g2(16, 2, 32);
    gemm2<<<g2, 512, 0, stream>>>(Yw, Dbf, out);
}